// Round 12
// baseline (683.421 us; speedup 1.0000x reference)
//
#include <hip/hip_runtime.h>
#include <hip/hip_bf16.h>

// ---------------- problem constants (match reference) ----------------
static constexpr int N_NODES = 100000;
static constexpr int N_EDGES = 3200000;
static constexpr int NFEAT   = 512;
static constexpr int NHID    = 256;
static constexpr int NCLASS  = 64;

static constexpr int SCAN_CHUNK = 2048;                       // 256 thr * 8 items
static constexpr int NB = (N_NODES + SCAN_CHUNK - 1) / SCAN_CHUNK; // 49

// dst-partitioned hist (kept from r4 — not the bottleneck)
static constexpr int PARTS = 8;
static constexpr int NODES_PER_PART = N_NODES / PARTS;         // 12500
static constexpr int EDGES_PER_BLOCK = 1024;                   // 256 thr * 4
static constexpr int NCHUNK = N_EDGES / EDGES_PER_BLOCK;       // 3125

// two-pass multi-split scatter (r11): 25 buckets of 4096 nodes
static constexpr int BUCK_SHIFT = 12;
static constexpr int NBUCK = (N_NODES + (1 << BUCK_SHIFT) - 1) >> BUCK_SHIFT;  // 25

using short8 = __attribute__((ext_vector_type(8))) short;
using f32x4  = __attribute__((ext_vector_type(4))) float;
using fv4    = __attribute__((ext_vector_type(4))) float;
using fv2    = __attribute__((ext_vector_type(2))) float;
using iv4    = __attribute__((ext_vector_type(4))) int;     // clang vector: ok for nontemporal builtins
using fvec4  = __attribute__((ext_vector_type(4))) float;

__device__ __forceinline__ short f2bf_bits(float f) {
    __hip_bfloat16 h = __float2bfloat16(f);
    return *reinterpret_cast<short*>(&h);
}

// fp8 (OCP e4m3) helpers — gfx950 v_cvt_pk_* instructions
__device__ __forceinline__ unsigned char f2fp8(float v) {
    int p = __builtin_amdgcn_cvt_pk_fp8_f32(v, v, 0, false);
    return (unsigned char)(p & 0xff);
}

// acc2[0..3] += w * fp8[0..7] (packed fv2 -> v_pk_fma_f32)
__device__ __forceinline__ void fp8x8_acc_pk(int vx, int vy, float w, fv2* acc2) {
    fv2 w2; w2[0] = w; w2[1] = w;
    acc2[0] += w2 * __builtin_amdgcn_cvt_pk_f32_fp8(vx, false);
    acc2[1] += w2 * __builtin_amdgcn_cvt_pk_f32_fp8(vx, true);
    acc2[2] += w2 * __builtin_amdgcn_cvt_pk_f32_fp8(vy, false);
    acc2[3] += w2 * __builtin_amdgcn_cvt_pk_f32_fp8(vy, true);
}

// acc2[0..7] += w * fp8[0..15] (16 cols from one 16B gather)
__device__ __forceinline__ void fp8x16_acc_pk(iv4 v, float w, fv2* acc2) {
    fp8x8_acc_pk(v.x, v.y, w, acc2);
    fp8x8_acc_pk(v.z, v.w, w, acc2 + 4);
}

#define GLOBAL_TO_LDS(gsrc, ldst)                                                        \
    __builtin_amdgcn_global_load_lds((const __attribute__((address_space(1))) void*)(gsrc), \
                                     (__attribute__((address_space(3))) void*)(ldst), 16, 0, 0)

// ---------------- CSR build ----------------
__global__ __launch_bounds__(256) void hist_part_kernel(const int* __restrict__ edst,
                                                        int* __restrict__ counts) {
    int p = blockIdx.x & (PARTS - 1);
    int chunk = blockIdx.x >> 3;
    int e0 = chunk * EDGES_PER_BLOCK + threadIdx.x * 4;
    int lo = p * NODES_PER_PART, hi = lo + NODES_PER_PART;
    iv4 d4 = __builtin_nontemporal_load((const iv4*)(edst + e0));
    int dd[4] = {d4.x, d4.y, d4.z, d4.w};
#pragma unroll
    for (int k = 0; k < 4; ++k)
        if (dd[k] >= lo && dd[k] < hi) atomicAdd(&counts[dd[k]], 1);
}

__global__ __launch_bounds__(256) void scan_part_kernel(const int* __restrict__ counts,
                                                        int* __restrict__ partials) {
    int b = blockIdx.x, t = threadIdx.x;
    int base = b * SCAN_CHUNK + t * 8;
    int s = 0;
#pragma unroll
    for (int j = 0; j < 8; ++j) {
        int i = base + j;
        if (i < N_NODES) s += counts[i];
    }
    __shared__ int sd[256];
    sd[t] = s;
    __syncthreads();
    for (int off = 128; off > 0; off >>= 1) {
        if (t < off) sd[t] += sd[t + off];
        __syncthreads();
    }
    if (t == 0) partials[b] = sd[0];
}

__global__ void scan_mid_kernel(int* __restrict__ partials) {
    if (threadIdx.x == 0) {
        int run = 0;
        for (int i = 0; i < NB; ++i) {
            int v = partials[i];
            partials[i] = run;
            run += v;
        }
    }
}

__global__ __launch_bounds__(256) void scan_final_kernel(int* __restrict__ counts_cursor,
                                                         int* __restrict__ row_ptr,
                                                         const int* __restrict__ partials) {
    int b = blockIdx.x, t = threadIdx.x;
    int base = b * SCAN_CHUNK + t * 8;
    int v[8];
    int tsum = 0;
#pragma unroll
    for (int j = 0; j < 8; ++j) {
        int i = base + j;
        v[j] = (i < N_NODES) ? counts_cursor[i] : 0;
        tsum += v[j];
    }
    __shared__ int sd[256];
    sd[t] = tsum;
    __syncthreads();
    for (int off = 1; off < 256; off <<= 1) {
        int x = (t >= off) ? sd[t - off] : 0;
        __syncthreads();
        sd[t] += x;
        __syncthreads();
    }
    int run = sd[t] - tsum + partials[b];
#pragma unroll
    for (int j = 0; j < 8; ++j) {
        int i = base + j;
        if (i < N_NODES) {
            row_ptr[i] = run;
            counts_cursor[i] = run;
        }
        run += v[j];
    }
    if (b == 0 && t == 0) row_ptr[N_NODES] = N_EDGES;
}

// bucket cursors seeded from row_ptr: bucket b's staging region coincides with the
// final pk range of its node span (exact capacity, no overlap).
__global__ void bucket_init_kernel(const int* __restrict__ row_ptr,
                                   int* __restrict__ bucket_cursor) {
    int t = threadIdx.x;
    if (t < NBUCK) {
        int node = t << BUCK_SHIFT;
        bucket_cursor[t] = row_ptr[node < N_NODES ? node : N_NODES];
    }
}

// Pass A: block-aggregated multi-split into NBUCK dst-buckets.
// Each (block,bucket) writes a contiguous ~41-entry run -> mostly full lines.
__global__ __launch_bounds__(256) void bin_kernel(const int* __restrict__ esrc,
                                                  const int* __restrict__ edst,
                                                  const float* __restrict__ ew,
                                                  int* __restrict__ bucket_cursor,
                                                  int2* __restrict__ spk_sw,
                                                  int* __restrict__ spk_d) {
    __shared__ int lcount[NBUCK];
    __shared__ int lbase[NBUCK];
    int tid = threadIdx.x;
    if (tid < NBUCK) lcount[tid] = 0;
    __syncthreads();
    int e0 = blockIdx.x * EDGES_PER_BLOCK + tid * 4;
    iv4   d4 = __builtin_nontemporal_load((const iv4*)(edst + e0));
    iv4   s4 = __builtin_nontemporal_load((const iv4*)(esrc + e0));
    fvec4 w4 = __builtin_nontemporal_load((const fvec4*)(ew + e0));
    int   dd[4] = {d4.x, d4.y, d4.z, d4.w};
    int   ss[4] = {s4.x, s4.y, s4.z, s4.w};
    float ww[4] = {w4.x, w4.y, w4.z, w4.w};
    int bi[4], rank[4];
#pragma unroll
    for (int k = 0; k < 4; ++k) {
        bi[k] = dd[k] >> BUCK_SHIFT;
        rank[k] = atomicAdd(&lcount[bi[k]], 1);
    }
    __syncthreads();
    if (tid < NBUCK) lbase[tid] = atomicAdd(&bucket_cursor[tid], lcount[tid]);
    __syncthreads();
#pragma unroll
    for (int k = 0; k < 4; ++k) {
        int pos = lbase[bi[k]] + rank[k];
        spk_sw[pos] = make_int2(ss[k], __float_as_int(ww[k]));
        spk_d[pos]  = dd[k];
    }
}

// Pass B: contiguous reads of staged bucket data; writes land in one bucket's ~1MB
// pk region, and the blocks touching it dispatch adjacently -> L2-absorbed,
// full-line writebacks.
__global__ __launch_bounds__(256) void scatter2_kernel(const int2* __restrict__ spk_sw,
                                                       const int* __restrict__ spk_d,
                                                       int* __restrict__ cursor,
                                                       int2* __restrict__ pk) {
    int e0 = blockIdx.x * EDGES_PER_BLOCK + threadIdx.x * 4;
    iv4 dd4 = __builtin_nontemporal_load((const iv4*)(spk_d + e0));
    iv4 q0  = __builtin_nontemporal_load((const iv4*)(spk_sw + e0));       // entries 0,1
    iv4 q1  = __builtin_nontemporal_load((const iv4*)(spk_sw + e0 + 2));   // entries 2,3
    int dd[4] = {dd4.x, dd4.y, dd4.z, dd4.w};
    int2 sw[4] = {make_int2(q0.x, q0.y), make_int2(q0.z, q0.w),
                  make_int2(q1.x, q1.y), make_int2(q1.z, q1.w)};
#pragma unroll
    for (int k = 0; k < 4; ++k) {
        int pos = atomicAdd(&cursor[dd[k]], 1);
        pk[pos] = sw[k];
    }
}

// ---------------- small transpose+cast: W[K][N] f32 -> WT[N][K] bf16 ----------------
__global__ __launch_bounds__(256) void transpose_w_kernel(const float* __restrict__ W,
                                                          __hip_bfloat16* __restrict__ WT,
                                                          int K, int N) {
    int idx = blockIdx.x * 256 + threadIdx.x;
    if (idx < K * N) {
        int k = idx / N, n = idx % N;
        WT[(size_t)n * K + k] = __float2bfloat16(W[idx]);
    }
}

// ---------------- GEMM1: support0[M,256](fp8) = A[M,512](f32) @ W1T[256,512]^T -------
__global__ __launch_bounds__(256) void gemm1_mfma(const float* __restrict__ A,
                                                  const __hip_bfloat16* __restrict__ BT,
                                                  unsigned char* __restrict__ C8,
                                                  int M) {
    constexpr int K = NFEAT;   // 512
    constexpr int N = NHID;    // 256
    constexpr int BM = 128, BN = 128, BK = 32;
    constexpr int NSTEP = K / BK;  // 16
    __shared__ __align__(16) float          As[2][BM * BK];  // 2 x 16 KB
    __shared__ __align__(16) __hip_bfloat16 Bs[2][BN * BK];  // 2 x 8 KB
    const int tid = threadIdx.x;
    const int lane = tid & 63, wave = tid >> 6;
    const int wr = wave >> 1, wc = wave & 1;
    const int laneRow = lane & 15, laneK = lane >> 4;
    const int row0 = blockIdx.x * BM;
    const int col0 = blockIdx.y * BN;

    f32x4 acc[4][4] = {};

    auto STAGE = [&](int step) {
        {
            float* dst = As[step & 1];
#pragma unroll
            for (int it = 0; it < 4; ++it) {
                int q = wave * 4 + it;
                int r = q * 8 + (lane >> 3);
                int c16 = lane & 7;
                int src_c = (c16 ^ ((r & 3) << 1)) * 4;  // floats
                int rg = row0 + r; rg = (rg < M) ? rg : (M - 1);
                const float* src = A + (size_t)rg * K + step * BK + src_c;
                GLOBAL_TO_LDS(src, dst + q * 256 + lane * 4);
            }
        }
        {
            __hip_bfloat16* dst = Bs[step & 1];
#pragma unroll
            for (int it = 0; it < 2; ++it) {
                int idx = tid + it * 256;
                int n = idx >> 2;
                int gk = (idx & 3) ^ ((n >> 1) & 3);
                const __hip_bfloat16* src = BT + (size_t)(col0 + n) * K + step * BK + gk * 8;
                GLOBAL_TO_LDS(src, dst + (size_t)idx * 8);
            }
        }
    };

    STAGE(0);

#pragma unroll
    for (int t = 0; t < NSTEP; ++t) {
        __syncthreads();                  // drains vmcnt: As/Bs[t&1] ready; prev readers done
        if (t + 1 < NSTEP) STAGE(t + 1);  // async prefetch; drained at next barrier
        short8 af[4];
#pragma unroll
        for (int i = 0; i < 4; ++i) {
            int rr = wr * 64 + i * 16 + laneRow;
            int ck = laneK ^ (rr & 3);
            const float* ap = As[t & 1] + rr * BK + ck * 8;
            fv4 a0 = *(const fv4*)ap;
            fv4 a1 = *(const fv4*)(ap + 4);
            short8 v;
#pragma unroll
            for (int j = 0; j < 4; ++j) v[j] = f2bf_bits(a0[j]);
#pragma unroll
            for (int j = 0; j < 4; ++j) v[4 + j] = f2bf_bits(a1[j]);
            af[i] = v;
        }
        short8 bfr[4];
#pragma unroll
        for (int j = 0; j < 4; ++j) {
            int n = wc * 64 + j * 16 + laneRow;
            int pg = laneK ^ ((n >> 1) & 3);
            bfr[j] = *(const short8*)(Bs[t & 1] + n * BK + pg * 8);
        }
#pragma unroll
        for (int i = 0; i < 4; ++i)
#pragma unroll
            for (int j = 0; j < 4; ++j)
                acc[i][j] = __builtin_amdgcn_mfma_f32_16x16x32_bf16(af[i], bfr[j], acc[i][j], 0, 0, 0);
    }
    // epilogue: C/D layout col=lane&15, row=(lane>>4)*4+q
#pragma unroll
    for (int i = 0; i < 4; ++i) {
        int rbase = row0 + wr * 64 + i * 16 + laneK * 4;
#pragma unroll
        for (int j = 0; j < 4; ++j) {
            int col = col0 + wc * 64 + j * 16 + laneRow;
#pragma unroll
            for (int q = 0; q < 4; ++q) {
                int row = rbase + q;
                if (row < M) C8[(size_t)row * N + col] = f2fp8(acc[i][j][q]);
            }
        }
    }
}

// ---------------- GEMM2: support1[M,64](fp8) = H0[M,256](bf16) @ W2T[64,256]^T ------
__global__ __launch_bounds__(256) void gemm2_mfma(const __hip_bfloat16* __restrict__ A,
                                                  const __hip_bfloat16* __restrict__ BT,
                                                  unsigned char* __restrict__ C8,
                                                  int M) {
    constexpr int K = NHID;    // 256
    constexpr int N = NCLASS;  // 64
    constexpr int BM = 128;
    __shared__ __align__(16) __hip_bfloat16 Bs[N * K];  // 32 KB
    const int tid = threadIdx.x;
    const int lane = tid & 63, wave = tid >> 6;
    const int wr = wave >> 1, wc = wave & 1;
    const int laneRow = lane & 15, laneK = lane >> 4;
    const int row0 = blockIdx.x * BM;

#pragma unroll
    for (int it = 0; it < 8; ++it) {
        int idx = tid + it * 256;
        int n = idx >> 5;
        int kk = (idx & 31) ^ (n & 7);
        const __hip_bfloat16* src = BT + (size_t)n * K + kk * 8;
        GLOBAL_TO_LDS(src, Bs + (size_t)idx * 8);
    }

    int arow[4];
#pragma unroll
    for (int i = 0; i < 4; ++i) {
        int r = row0 + wr * 64 + i * 16 + laneRow;
        arow[i] = (r < M) ? r : (M - 1);
    }

    f32x4 acc[4][2] = {};
    __syncthreads();

#pragma unroll
    for (int k0 = 0; k0 < K; k0 += 32) {
        short8 af[4];
#pragma unroll
        for (int i = 0; i < 4; ++i)
            af[i] = *(const short8*)(A + (size_t)arow[i] * K + k0 + laneK * 8);
        short8 bfr[2];
#pragma unroll
        for (int j = 0; j < 2; ++j) {
            int n = wc * 32 + j * 16 + laneRow;
            int kkw = (k0 >> 3) + laneK;
            int pkk = kkw ^ (n & 7);
            bfr[j] = *(const short8*)(Bs + (size_t)n * 32 * 8 + pkk * 8);
        }
#pragma unroll
        for (int i = 0; i < 4; ++i)
#pragma unroll
            for (int j = 0; j < 2; ++j)
                acc[i][j] = __builtin_amdgcn_mfma_f32_16x16x32_bf16(af[i], bfr[j], acc[i][j], 0, 0, 0);
    }

#pragma unroll
    for (int i = 0; i < 4; ++i) {
        int rbase = row0 + wr * 64 + i * 16 + laneK * 4;
#pragma unroll
        for (int j = 0; j < 2; ++j) {
            int col = wc * 32 + j * 16 + laneRow;
#pragma unroll
            for (int q = 0; q < 4; ++q) {
                int row = rbase + q;
                if (row < M) C8[(size_t)row * N + col] = f2fp8(acc[i][j][q]);
            }
        }
    }
}

// ---------------- SPMM layer1: one wave = one node = FULL 256-col row.
// Lanes = 4 edge slots (lane>>4) x 16 chunks of 16 cols (16B gather per lane).
// x2 unroll -> 8 edges in flight per wave; packed fv2 accumulate (v_pk_fma_f32).
__global__ __launch_bounds__(256) void spmm1_kernel(const unsigned char* __restrict__ s0_8,
                                                    const int* __restrict__ row_ptr,
                                                    const int2* __restrict__ pk,
                                                    const float* __restrict__ b1,
                                                    __hip_bfloat16* __restrict__ H0) {
    int node = blockIdx.x * 4 + (threadIdx.x >> 6);
    int lane = threadIdx.x & 63;
    int j = lane >> 4;                 // edge slot 0..3
    int c = lane & 15;                 // column chunk (16 cols each) -> 256 cols
    int coff = c * 16;
    int beg = row_ptr[node], end = row_ptr[node + 1];
    fv2 acc2[8] = {};
    for (int base = beg; base + j < end; base += 8) {
        int2 pe0 = pk[base + j];
        int i1 = base + 4 + j;
        int2 pe1 = (i1 < end) ? pk[i1] : make_int2(0, 0);
        float w0 = __int_as_float(pe0.y);
        float w1 = __int_as_float(pe1.y);
        iv4 v0 = *(const iv4*)(s0_8 + (size_t)pe0.x * NHID + coff);
        iv4 v1 = *(const iv4*)(s0_8 + (size_t)pe1.x * NHID + coff);
        fp8x16_acc_pk(v0, w0, acc2);
        fp8x16_acc_pk(v1, w1, acc2);
    }
    float accf[16];
#pragma unroll
    for (int k = 0; k < 8; ++k) { accf[2 * k] = acc2[k][0]; accf[2 * k + 1] = acc2[k][1]; }
#pragma unroll
    for (int m = 16; m < 64; m <<= 1)
#pragma unroll
        for (int k = 0; k < 16; ++k) accf[k] += __shfl_xor(accf[k], m);
    if (lane < 16) {
        short8 o0, o1;
#pragma unroll
        for (int k = 0; k < 8; ++k)  o0[k] = f2bf_bits(fmaxf(accf[k] + b1[coff + k], 0.f));
#pragma unroll
        for (int k = 0; k < 8; ++k)  o1[k] = f2bf_bits(fmaxf(accf[8 + k] + b1[coff + 8 + k], 0.f));
        __hip_bfloat16* dst = H0 + (size_t)node * NHID + coff;
        *(short8*)dst = o0;
        *(short8*)(dst + 8) = o1;
    }
}

// ---------------- SPMM layer2 + bias + log_softmax (fp8 gather, 8x8, x2 unroll,
// packed fv2 accumulate) ---------------------------------------------------------------
__global__ __launch_bounds__(256) void spmm2_softmax_kernel(const unsigned char* __restrict__ s1_8,
                                                            const int* __restrict__ row_ptr,
                                                            const int2* __restrict__ pk,
                                                            const float* __restrict__ b2,
                                                            float* __restrict__ out) {
    int node = blockIdx.x * 4 + (threadIdx.x >> 6);
    int lane = threadIdx.x & 63;
    int j = lane >> 3;   // edge slot 0..7
    int c = lane & 7;    // class chunk (8 classes each)
    int beg = row_ptr[node], end = row_ptr[node + 1];
    fv2 acc2[4] = {};
    for (int base = beg; base + j < end; base += 16) {
        int2 pe0 = pk[base + j];
        int i1 = base + 8 + j;
        int2 pe1 = (i1 < end) ? pk[i1] : make_int2(0, 0);
        float w0 = __int_as_float(pe0.y);
        float w1 = __int_as_float(pe1.y);
        int2 v0 = *(const int2*)(s1_8 + (size_t)pe0.x * NCLASS + c * 8);
        int2 v1 = *(const int2*)(s1_8 + (size_t)pe1.x * NCLASS + c * 8);
        fp8x8_acc_pk(v0.x, v0.y, w0, acc2);
        fp8x8_acc_pk(v1.x, v1.y, w1, acc2);
    }
    float acc[8];
#pragma unroll
    for (int k = 0; k < 4; ++k) { acc[2 * k] = acc2[k][0]; acc[2 * k + 1] = acc2[k][1]; }
#pragma unroll
    for (int m = 8; m < 64; m <<= 1)
#pragma unroll
        for (int k = 0; k < 8; ++k) acc[k] += __shfl_xor(acc[k], m);

    fv4 blo = *(const fv4*)(b2 + c * 8);
    fv4 bhi = *(const fv4*)(b2 + c * 8 + 4);
    float z[8];
#pragma unroll
    for (int k = 0; k < 4; ++k) z[k] = acc[k] + blo[k];
#pragma unroll
    for (int k = 0; k < 4; ++k) z[4 + k] = acc[4 + k] + bhi[k];

    float mx = z[0];
#pragma unroll
    for (int k = 1; k < 8; ++k) mx = fmaxf(mx, z[k]);
#pragma unroll
    for (int m = 1; m < 8; m <<= 1) mx = fmaxf(mx, __shfl_xor(mx, m));
    float s = 0.f;
#pragma unroll
    for (int k = 0; k < 8; ++k) s += __expf(z[k] - mx);
#pragma unroll
    for (int m = 1; m < 8; m <<= 1) s += __shfl_xor(s, m);
    float lg = __logf(s);
    if (lane < 8) {
        f32x4 o0, o1;
#pragma unroll
        for (int k = 0; k < 4; ++k) o0[k] = z[k] - mx - lg;
#pragma unroll
        for (int k = 0; k < 4; ++k) o1[k] = z[4 + k] - mx - lg;
        float* dst = out + (size_t)node * NCLASS + c * 8;
        *(f32x4*)dst = o0;
        *(f32x4*)(dst + 4) = o1;
    }
}

// ---------------- host launch ----------------
extern "C" void kernel_launch(void* const* d_in, const int* in_sizes, int n_in,
                              void* d_out, int out_size, void* d_ws, size_t ws_size,
                              hipStream_t stream) {
    const float* x    = (const float*)d_in[0];
    const int*   esrc = (const int*)d_in[1];
    const int*   edst = (const int*)d_in[2];
    const float* ew   = (const float*)d_in[3];
    const float* W1   = (const float*)d_in[4];
    const float* b1   = (const float*)d_in[5];
    const float* W2   = (const float*)d_in[6];
    const float* b2   = (const float*)d_in[7];
    float* out = (float*)d_out;

    char* ws = (char*)d_ws;
    size_t off = 0;
    auto alloc = [&](size_t bytes) {
        size_t o = off;
        off = (off + bytes + 255) & ~(size_t)255;
        return o;
    };
    unsigned char* support0 = (unsigned char*)(ws + alloc((size_t)N_NODES * NHID));
    __hip_bfloat16* H0      = (__hip_bfloat16*)(ws + alloc((size_t)N_NODES * NHID * 2));
    unsigned char* support1 = (unsigned char*)(ws + alloc((size_t)N_NODES * NCLASS));
    int2*  pk         = (int2*)(ws + alloc((size_t)N_EDGES * 8));
    int2*  spk_sw     = (int2*)(ws + alloc((size_t)N_EDGES * 8));
    int*   spk_d      = (int*)(ws + alloc((size_t)N_EDGES * 4));
    int*   row_ptr    = (int*)(ws + alloc((size_t)(N_NODES + 1) * 4));
    int*   cursor     = (int*)(ws + alloc((size_t)N_NODES * 4));
    int*   partials   = (int*)(ws + alloc(256 * 4));
    int*   bucket_cursor = (int*)(ws + alloc(64 * 4));
    __hip_bfloat16* W1T = (__hip_bfloat16*)(ws + alloc((size_t)NHID * NFEAT * 2));
    __hip_bfloat16* W2T = (__hip_bfloat16*)(ws + alloc((size_t)NCLASS * NHID * 2));

    // --- weight transposes (bf16) ---
    transpose_w_kernel<<<(NFEAT * NHID + 255) / 256, 256, 0, stream>>>(W1, W1T, NFEAT, NHID);
    transpose_w_kernel<<<(NHID * NCLASS + 255) / 256, 256, 0, stream>>>(W2, W2T, NHID, NCLASS);

    // --- CSR build: hist -> scan -> two-pass multi-split scatter ---
    hipMemsetAsync(cursor, 0, (size_t)N_NODES * 4, stream);
    hist_part_kernel<<<NCHUNK * PARTS, 256, 0, stream>>>(edst, cursor);
    scan_part_kernel<<<NB, 256, 0, stream>>>(cursor, partials);
    scan_mid_kernel<<<1, 64, 0, stream>>>(partials);
    scan_final_kernel<<<NB, 256, 0, stream>>>(cursor, row_ptr, partials);
    bucket_init_kernel<<<1, 64, 0, stream>>>(row_ptr, bucket_cursor);
    bin_kernel<<<NCHUNK, 256, 0, stream>>>(esrc, edst, ew, bucket_cursor, spk_sw, spk_d);
    scatter2_kernel<<<NCHUNK, 256, 0, stream>>>(spk_sw, spk_d, cursor, pk);

    // --- Layer 1 ---
    gemm1_mfma<<<dim3((N_NODES + 127) / 128, 2), 256, 0, stream>>>(x, W1T, support0, N_NODES);
    spmm1_kernel<<<N_NODES / 4, 256, 0, stream>>>(support0, row_ptr, pk, b1, H0);

    // --- Layer 2 ---
    gemm2_mfma<<<(N_NODES + 127) / 128, 256, 0, stream>>>(H0, W2T, support1, N_NODES);
    spmm2_softmax_kernel<<<N_NODES / 4, 256, 0, stream>>>(support1, row_ptr, pk, b2, out);
}

// Round 13
// 589.375 us; speedup vs baseline: 1.1596x; 1.1596x over previous
//
#include <hip/hip_runtime.h>
#include <hip/hip_bf16.h>

// ---------------- problem constants (match reference) ----------------
static constexpr int N_NODES = 100000;
static constexpr int N_EDGES = 3200000;
static constexpr int NFEAT   = 512;
static constexpr int NHID    = 256;
static constexpr int NCLASS  = 64;

static constexpr int SCAN_CHUNK = 2048;                       // 256 thr * 8 items
static constexpr int NB = (N_NODES + SCAN_CHUNK - 1) / SCAN_CHUNK; // 49

static constexpr int PARTS = 8;
static constexpr int NODES_PER_PART = N_NODES / PARTS;         // 12500
static constexpr int EDGES_PER_BLOCK = 1024;                   // 256 thr * 4
static constexpr int NCHUNK = N_EDGES / EDGES_PER_BLOCK;       // 3125

using short8 = __attribute__((ext_vector_type(8))) short;
using f32x4  = __attribute__((ext_vector_type(4))) float;
using fv4    = __attribute__((ext_vector_type(4))) float;
using fv2    = __attribute__((ext_vector_type(2))) float;
using iv4    = __attribute__((ext_vector_type(4))) int;     // clang vector: ok for nontemporal builtins
using iv2    = __attribute__((ext_vector_type(2))) int;
using fvec4  = __attribute__((ext_vector_type(4))) float;

__device__ __forceinline__ short f2bf_bits(float f) {
    __hip_bfloat16 h = __float2bfloat16(f);
    return *reinterpret_cast<short*>(&h);
}

// fp8 (OCP e4m3) helpers — gfx950 v_cvt_pk_* instructions
__device__ __forceinline__ unsigned char f2fp8(float v) {
    int p = __builtin_amdgcn_cvt_pk_fp8_f32(v, v, 0, false);
    return (unsigned char)(p & 0xff);
}

// acc2[0..3] += w * fp8[0..7] (packed fv2 -> v_pk_fma_f32)
__device__ __forceinline__ void fp8x8_acc_pk(int vx, int vy, float w, fv2* acc2) {
    fv2 w2; w2[0] = w; w2[1] = w;
    acc2[0] += w2 * __builtin_amdgcn_cvt_pk_f32_fp8(vx, false);
    acc2[1] += w2 * __builtin_amdgcn_cvt_pk_f32_fp8(vx, true);
    acc2[2] += w2 * __builtin_amdgcn_cvt_pk_f32_fp8(vy, false);
    acc2[3] += w2 * __builtin_amdgcn_cvt_pk_f32_fp8(vy, true);
}

// acc2[0..7] += w * fp8[0..15] (16 cols from one 16B gather)
__device__ __forceinline__ void fp8x16_acc_pk(iv4 v, float w, fv2* acc2) {
    fp8x8_acc_pk(v.x, v.y, w, acc2);
    fp8x8_acc_pk(v.z, v.w, w, acc2 + 4);
}

#define GLOBAL_TO_LDS(gsrc, ldst)                                                        \
    __builtin_amdgcn_global_load_lds((const __attribute__((address_space(1))) void*)(gsrc), \
                                     (__attribute__((address_space(3))) void*)(ldst), 16, 0, 0)

// ---------------- CSR build ----------------
// Single-pass hist (r13): edges read once (12.8 MB vs 102 MB for the 8x partitioned
// version — partitioning provably bought nothing for the write side, r11/r12).
__global__ __launch_bounds__(256) void hist_kernel(const int* __restrict__ edst,
                                                   int* __restrict__ counts) {
    int e0 = blockIdx.x * EDGES_PER_BLOCK + threadIdx.x * 4;
    iv4 d4 = __builtin_nontemporal_load((const iv4*)(edst + e0));
    atomicAdd(&counts[d4.x], 1);
    atomicAdd(&counts[d4.y], 1);
    atomicAdd(&counts[d4.z], 1);
    atomicAdd(&counts[d4.w], 1);
}

__global__ __launch_bounds__(256) void scan_part_kernel(const int* __restrict__ counts,
                                                        int* __restrict__ partials) {
    int b = blockIdx.x, t = threadIdx.x;
    int base = b * SCAN_CHUNK + t * 8;
    int s = 0;
#pragma unroll
    for (int j = 0; j < 8; ++j) {
        int i = base + j;
        if (i < N_NODES) s += counts[i];
    }
    __shared__ int sd[256];
    sd[t] = s;
    __syncthreads();
    for (int off = 128; off > 0; off >>= 1) {
        if (t < off) sd[t] += sd[t + off];
        __syncthreads();
    }
    if (t == 0) partials[b] = sd[0];
}

__global__ void scan_mid_kernel(int* __restrict__ partials) {
    if (threadIdx.x == 0) {
        int run = 0;
        for (int i = 0; i < NB; ++i) {
            int v = partials[i];
            partials[i] = run;
            run += v;
        }
    }
}

__global__ __launch_bounds__(256) void scan_final_kernel(int* __restrict__ counts_cursor,
                                                         int* __restrict__ row_ptr,
                                                         const int* __restrict__ partials) {
    int b = blockIdx.x, t = threadIdx.x;
    int base = b * SCAN_CHUNK + t * 8;
    int v[8];
    int tsum = 0;
#pragma unroll
    for (int j = 0; j < 8; ++j) {
        int i = base + j;
        v[j] = (i < N_NODES) ? counts_cursor[i] : 0;
        tsum += v[j];
    }
    __shared__ int sd[256];
    sd[t] = tsum;
    __syncthreads();
    for (int off = 1; off < 256; off <<= 1) {
        int x = (t >= off) ? sd[t - off] : 0;
        __syncthreads();
        sd[t] += x;
        __syncthreads();
    }
    int run = sd[t] - tsum + partials[b];
#pragma unroll
    for (int j = 0; j < 8; ++j) {
        int i = base + j;
        if (i < N_NODES) {
            row_ptr[i] = run;
            counts_cursor[i] = run;
        }
        run += v[j];
    }
    if (b == 0 && t == 0) row_ptr[N_NODES] = N_EDGES;
}

// Single-pass partitioned scatter (r11 structure, known 146us) + r13 probe:
// NON-TEMPORAL pk stores (streaming, no-allocate) — tests whether the memory side
// can merge partial-line writes without the L2 dirty-line RMW (the 165-205 MB
// WRITE_SIZE floor seen in r4..r12).
__global__ __launch_bounds__(256) void scatter_part_kernel(const int* __restrict__ esrc,
                                                           const int* __restrict__ edst,
                                                           const float* __restrict__ ew,
                                                           int* __restrict__ cursor,
                                                           int2* __restrict__ pk) {
    int p = blockIdx.x & (PARTS - 1);
    int chunk = blockIdx.x >> 3;
    int e0 = chunk * EDGES_PER_BLOCK + threadIdx.x * 4;
    int lo = p * NODES_PER_PART, hi = lo + NODES_PER_PART;
    iv4   d4 = __builtin_nontemporal_load((const iv4*)(edst + e0));
    iv4   s4 = __builtin_nontemporal_load((const iv4*)(esrc + e0));
    fvec4 w4 = __builtin_nontemporal_load((const fvec4*)(ew + e0));
    int   dd[4] = {d4.x, d4.y, d4.z, d4.w};
    int   ss[4] = {s4.x, s4.y, s4.z, s4.w};
    float ww[4] = {w4.x, w4.y, w4.z, w4.w};
#pragma unroll
    for (int k = 0; k < 4; ++k) {
        if (dd[k] >= lo && dd[k] < hi) {
            int pos = atomicAdd(&cursor[dd[k]], 1);
            iv2 val; val.x = ss[k]; val.y = __float_as_int(ww[k]);
            __builtin_nontemporal_store(val, (iv2*)(pk + pos));
        }
    }
}

// ---------------- small transpose+cast: W[K][N] f32 -> WT[N][K] bf16 ----------------
__global__ __launch_bounds__(256) void transpose_w_kernel(const float* __restrict__ W,
                                                          __hip_bfloat16* __restrict__ WT,
                                                          int K, int N) {
    int idx = blockIdx.x * 256 + threadIdx.x;
    if (idx < K * N) {
        int k = idx / N, n = idx % N;
        WT[(size_t)n * K + k] = __float2bfloat16(W[idx]);
    }
}

// ---------------- GEMM1: support0[M,256](fp8) = A[M,512](f32) @ W1T[256,512]^T -------
// 128x128 tile (grid.y=2 col-blocks), 4 waves (2x2), 4x4 fragments of 16x16x32 MFMA.
// BOTH A and B staged via global_load_lds, double-buffered (48 KB LDS -> 3 blocks/CU).
__global__ __launch_bounds__(256) void gemm1_mfma(const float* __restrict__ A,
                                                  const __hip_bfloat16* __restrict__ BT,
                                                  unsigned char* __restrict__ C8,
                                                  int M) {
    constexpr int K = NFEAT;   // 512
    constexpr int N = NHID;    // 256
    constexpr int BM = 128, BN = 128, BK = 32;
    constexpr int NSTEP = K / BK;  // 16
    __shared__ __align__(16) float          As[2][BM * BK];  // 2 x 16 KB
    __shared__ __align__(16) __hip_bfloat16 Bs[2][BN * BK];  // 2 x 8 KB
    const int tid = threadIdx.x;
    const int lane = tid & 63, wave = tid >> 6;
    const int wr = wave >> 1, wc = wave & 1;
    const int laneRow = lane & 15, laneK = lane >> 4;
    const int row0 = blockIdx.x * BM;
    const int col0 = blockIdx.y * BN;

    f32x4 acc[4][4] = {};

    auto STAGE = [&](int step) {
        {
            float* dst = As[step & 1];
#pragma unroll
            for (int it = 0; it < 4; ++it) {
                int q = wave * 4 + it;
                int r = q * 8 + (lane >> 3);
                int c16 = lane & 7;
                int src_c = (c16 ^ ((r & 3) << 1)) * 4;  // floats
                int rg = row0 + r; rg = (rg < M) ? rg : (M - 1);
                const float* src = A + (size_t)rg * K + step * BK + src_c;
                GLOBAL_TO_LDS(src, dst + q * 256 + lane * 4);
            }
        }
        {
            __hip_bfloat16* dst = Bs[step & 1];
#pragma unroll
            for (int it = 0; it < 2; ++it) {
                int idx = tid + it * 256;
                int n = idx >> 2;
                int gk = (idx & 3) ^ ((n >> 1) & 3);
                const __hip_bfloat16* src = BT + (size_t)(col0 + n) * K + step * BK + gk * 8;
                GLOBAL_TO_LDS(src, dst + (size_t)idx * 8);
            }
        }
    };

    STAGE(0);

#pragma unroll
    for (int t = 0; t < NSTEP; ++t) {
        __syncthreads();                  // drains vmcnt: As/Bs[t&1] ready; prev readers done
        if (t + 1 < NSTEP) STAGE(t + 1);  // async prefetch; drained at next barrier
        short8 af[4];
#pragma unroll
        for (int i = 0; i < 4; ++i) {
            int rr = wr * 64 + i * 16 + laneRow;
            int ck = laneK ^ (rr & 3);
            const float* ap = As[t & 1] + rr * BK + ck * 8;
            fv4 a0 = *(const fv4*)ap;
            fv4 a1 = *(const fv4*)(ap + 4);
            short8 v;
#pragma unroll
            for (int j = 0; j < 4; ++j) v[j] = f2bf_bits(a0[j]);
#pragma unroll
            for (int j = 0; j < 4; ++j) v[4 + j] = f2bf_bits(a1[j]);
            af[i] = v;
        }
        short8 bfr[4];
#pragma unroll
        for (int j = 0; j < 4; ++j) {
            int n = wc * 64 + j * 16 + laneRow;
            int pg = laneK ^ ((n >> 1) & 3);
            bfr[j] = *(const short8*)(Bs[t & 1] + n * BK + pg * 8);
        }
#pragma unroll
        for (int i = 0; i < 4; ++i)
#pragma unroll
            for (int j = 0; j < 4; ++j)
                acc[i][j] = __builtin_amdgcn_mfma_f32_16x16x32_bf16(af[i], bfr[j], acc[i][j], 0, 0, 0);
    }
    // epilogue: C/D layout col=lane&15, row=(lane>>4)*4+q
#pragma unroll
    for (int i = 0; i < 4; ++i) {
        int rbase = row0 + wr * 64 + i * 16 + laneK * 4;
#pragma unroll
        for (int j = 0; j < 4; ++j) {
            int col = col0 + wc * 64 + j * 16 + laneRow;
#pragma unroll
            for (int q = 0; q < 4; ++q) {
                int row = rbase + q;
                if (row < M) C8[(size_t)row * N + col] = f2fp8(acc[i][j][q]);
            }
        }
    }
}

// ---------------- GEMM2: support1[M,64](fp8) = H0[M,256](bf16) @ W2T[64,256]^T ------
__global__ __launch_bounds__(256) void gemm2_mfma(const __hip_bfloat16* __restrict__ A,
                                                  const __hip_bfloat16* __restrict__ BT,
                                                  unsigned char* __restrict__ C8,
                                                  int M) {
    constexpr int K = NHID;    // 256
    constexpr int N = NCLASS;  // 64
    constexpr int BM = 128;
    __shared__ __align__(16) __hip_bfloat16 Bs[N * K];  // 32 KB
    const int tid = threadIdx.x;
    const int lane = tid & 63, wave = tid >> 6;
    const int wr = wave >> 1, wc = wave & 1;
    const int laneRow = lane & 15, laneK = lane >> 4;
    const int row0 = blockIdx.x * BM;

#pragma unroll
    for (int it = 0; it < 8; ++it) {
        int idx = tid + it * 256;
        int n = idx >> 5;
        int kk = (idx & 31) ^ (n & 7);
        const __hip_bfloat16* src = BT + (size_t)n * K + kk * 8;
        GLOBAL_TO_LDS(src, Bs + (size_t)idx * 8);
    }

    int arow[4];
#pragma unroll
    for (int i = 0; i < 4; ++i) {
        int r = row0 + wr * 64 + i * 16 + laneRow;
        arow[i] = (r < M) ? r : (M - 1);
    }

    f32x4 acc[4][2] = {};
    __syncthreads();

#pragma unroll
    for (int k0 = 0; k0 < K; k0 += 32) {
        short8 af[4];
#pragma unroll
        for (int i = 0; i < 4; ++i)
            af[i] = *(const short8*)(A + (size_t)arow[i] * K + k0 + laneK * 8);
        short8 bfr[2];
#pragma unroll
        for (int j = 0; j < 2; ++j) {
            int n = wc * 32 + j * 16 + laneRow;
            int kkw = (k0 >> 3) + laneK;
            int pkk = kkw ^ (n & 7);
            bfr[j] = *(const short8*)(Bs + (size_t)n * 32 * 8 + pkk * 8);
        }
#pragma unroll
        for (int i = 0; i < 4; ++i)
#pragma unroll
            for (int j = 0; j < 2; ++j)
                acc[i][j] = __builtin_amdgcn_mfma_f32_16x16x32_bf16(af[i], bfr[j], acc[i][j], 0, 0, 0);
    }

#pragma unroll
    for (int i = 0; i < 4; ++i) {
        int rbase = row0 + wr * 64 + i * 16 + laneK * 4;
#pragma unroll
        for (int j = 0; j < 2; ++j) {
            int col = wc * 32 + j * 16 + laneRow;
#pragma unroll
            for (int q = 0; q < 4; ++q) {
                int row = rbase + q;
                if (row < M) C8[(size_t)row * N + col] = f2fp8(acc[i][j][q]);
            }
        }
    }
}

// ---------------- SPMM layer1: one wave = one node = FULL 256-col row.
// Lanes = 4 edge slots (lane>>4) x 16 chunks of 16 cols (16B gather per lane).
// x2 unroll -> 8 edges in flight per wave; packed fv2 accumulate (v_pk_fma_f32).
__global__ __launch_bounds__(256) void spmm1_kernel(const unsigned char* __restrict__ s0_8,
                                                    const int* __restrict__ row_ptr,
                                                    const int2* __restrict__ pk,
                                                    const float* __restrict__ b1,
                                                    __hip_bfloat16* __restrict__ H0) {
    int node = blockIdx.x * 4 + (threadIdx.x >> 6);
    int lane = threadIdx.x & 63;
    int j = lane >> 4;                 // edge slot 0..3
    int c = lane & 15;                 // column chunk (16 cols each) -> 256 cols
    int coff = c * 16;
    int beg = row_ptr[node], end = row_ptr[node + 1];
    fv2 acc2[8] = {};
    for (int base = beg; base + j < end; base += 8) {
        int2 pe0 = pk[base + j];
        int i1 = base + 4 + j;
        int2 pe1 = (i1 < end) ? pk[i1] : make_int2(0, 0);
        float w0 = __int_as_float(pe0.y);
        float w1 = __int_as_float(pe1.y);
        iv4 v0 = *(const iv4*)(s0_8 + (size_t)pe0.x * NHID + coff);
        iv4 v1 = *(const iv4*)(s0_8 + (size_t)pe1.x * NHID + coff);
        fp8x16_acc_pk(v0, w0, acc2);
        fp8x16_acc_pk(v1, w1, acc2);
    }
    float accf[16];
#pragma unroll
    for (int k = 0; k < 8; ++k) { accf[2 * k] = acc2[k][0]; accf[2 * k + 1] = acc2[k][1]; }
#pragma unroll
    for (int m = 16; m < 64; m <<= 1)
#pragma unroll
        for (int k = 0; k < 16; ++k) accf[k] += __shfl_xor(accf[k], m);
    if (lane < 16) {
        short8 o0, o1;
#pragma unroll
        for (int k = 0; k < 8; ++k)  o0[k] = f2bf_bits(fmaxf(accf[k] + b1[coff + k], 0.f));
#pragma unroll
        for (int k = 0; k < 8; ++k)  o1[k] = f2bf_bits(fmaxf(accf[8 + k] + b1[coff + 8 + k], 0.f));
        __hip_bfloat16* dst = H0 + (size_t)node * NHID + coff;
        *(short8*)dst = o0;
        *(short8*)(dst + 8) = o1;
    }
}

// ---------------- SPMM layer2 + bias + log_softmax (fp8 gather, 8x8, x2 unroll,
// packed fv2 accumulate) ---------------------------------------------------------------
__global__ __launch_bounds__(256) void spmm2_softmax_kernel(const unsigned char* __restrict__ s1_8,
                                                            const int* __restrict__ row_ptr,
                                                            const int2* __restrict__ pk,
                                                            const float* __restrict__ b2,
                                                            float* __restrict__ out) {
    int node = blockIdx.x * 4 + (threadIdx.x >> 6);
    int lane = threadIdx.x & 63;
    int j = lane >> 3;   // edge slot 0..7
    int c = lane & 7;    // class chunk (8 classes each)
    int beg = row_ptr[node], end = row_ptr[node + 1];
    fv2 acc2[4] = {};
    for (int base = beg; base + j < end; base += 16) {
        int2 pe0 = pk[base + j];
        int i1 = base + 8 + j;
        int2 pe1 = (i1 < end) ? pk[i1] : make_int2(0, 0);
        float w0 = __int_as_float(pe0.y);
        float w1 = __int_as_float(pe1.y);
        int2 v0 = *(const int2*)(s1_8 + (size_t)pe0.x * NCLASS + c * 8);
        int2 v1 = *(const int2*)(s1_8 + (size_t)pe1.x * NCLASS + c * 8);
        fp8x8_acc_pk(v0.x, v0.y, w0, acc2);
        fp8x8_acc_pk(v1.x, v1.y, w1, acc2);
    }
    float acc[8];
#pragma unroll
    for (int k = 0; k < 4; ++k) { acc[2 * k] = acc2[k][0]; acc[2 * k + 1] = acc2[k][1]; }
#pragma unroll
    for (int m = 8; m < 64; m <<= 1)
#pragma unroll
        for (int k = 0; k < 8; ++k) acc[k] += __shfl_xor(acc[k], m);

    fv4 blo = *(const fv4*)(b2 + c * 8);
    fv4 bhi = *(const fv4*)(b2 + c * 8 + 4);
    float z[8];
#pragma unroll
    for (int k = 0; k < 4; ++k) z[k] = acc[k] + blo[k];
#pragma unroll
    for (int k = 0; k < 4; ++k) z[4 + k] = acc[4 + k] + bhi[k];

    float mx = z[0];
#pragma unroll
    for (int k = 1; k < 8; ++k) mx = fmaxf(mx, z[k]);
#pragma unroll
    for (int m = 1; m < 8; m <<= 1) mx = fmaxf(mx, __shfl_xor(mx, m));
    float s = 0.f;
#pragma unroll
    for (int k = 0; k < 8; ++k) s += __expf(z[k] - mx);
#pragma unroll
    for (int m = 1; m < 8; m <<= 1) s += __shfl_xor(s, m);
    float lg = __logf(s);
    if (lane < 8) {
        f32x4 o0, o1;
#pragma unroll
        for (int k = 0; k < 4; ++k) o0[k] = z[k] - mx - lg;
#pragma unroll
        for (int k = 0; k < 4; ++k) o1[k] = z[4 + k] - mx - lg;
        float* dst = out + (size_t)node * NCLASS + c * 8;
        *(f32x4*)dst = o0;
        *(f32x4*)(dst + 4) = o1;
    }
}

// ---------------- host launch ----------------
extern "C" void kernel_launch(void* const* d_in, const int* in_sizes, int n_in,
                              void* d_out, int out_size, void* d_ws, size_t ws_size,
                              hipStream_t stream) {
    const float* x    = (const float*)d_in[0];
    const int*   esrc = (const int*)d_in[1];
    const int*   edst = (const int*)d_in[2];
    const float* ew   = (const float*)d_in[3];
    const float* W1   = (const float*)d_in[4];
    const float* b1   = (const float*)d_in[5];
    const float* W2   = (const float*)d_in[6];
    const float* b2   = (const float*)d_in[7];
    float* out = (float*)d_out;

    char* ws = (char*)d_ws;
    size_t off = 0;
    auto alloc = [&](size_t bytes) {
        size_t o = off;
        off = (off + bytes + 255) & ~(size_t)255;
        return o;
    };
    unsigned char* support0 = (unsigned char*)(ws + alloc((size_t)N_NODES * NHID));
    __hip_bfloat16* H0      = (__hip_bfloat16*)(ws + alloc((size_t)N_NODES * NHID * 2));
    unsigned char* support1 = (unsigned char*)(ws + alloc((size_t)N_NODES * NCLASS));
    int2*  pk         = (int2*)(ws + alloc((size_t)N_EDGES * 8));
    int*   row_ptr    = (int*)(ws + alloc((size_t)(N_NODES + 1) * 4));
    int*   cursor     = (int*)(ws + alloc((size_t)N_NODES * 4));
    int*   partials   = (int*)(ws + alloc(256 * 4));
    __hip_bfloat16* W1T = (__hip_bfloat16*)(ws + alloc((size_t)NHID * NFEAT * 2));
    __hip_bfloat16* W2T = (__hip_bfloat16*)(ws + alloc((size_t)NCLASS * NHID * 2));

    // --- weight transposes (bf16) ---
    transpose_w_kernel<<<(NFEAT * NHID + 255) / 256, 256, 0, stream>>>(W1, W1T, NFEAT, NHID);
    transpose_w_kernel<<<(NHID * NCLASS + 255) / 256, 256, 0, stream>>>(W2, W2T, NHID, NCLASS);

    // --- CSR build: single-pass hist -> scan -> single-pass scatter (nt stores) ---
    hipMemsetAsync(cursor, 0, (size_t)N_NODES * 4, stream);
    hist_kernel<<<NCHUNK, 256, 0, stream>>>(edst, cursor);
    scan_part_kernel<<<NB, 256, 0, stream>>>(cursor, partials);
    scan_mid_kernel<<<1, 64, 0, stream>>>(partials);
    scan_final_kernel<<<NB, 256, 0, stream>>>(cursor, row_ptr, partials);
    scatter_part_kernel<<<NCHUNK * PARTS, 256, 0, stream>>>(esrc, edst, ew, cursor, pk);

    // --- Layer 1 ---
    gemm1_mfma<<<dim3((N_NODES + 127) / 128, 2), 256, 0, stream>>>(x, W1T, support0, N_NODES);
    spmm1_kernel<<<N_NODES / 4, 256, 0, stream>>>(support0, row_ptr, pk, b1, H0);

    // --- Layer 2 ---
    gemm2_mfma<<<(N_NODES + 127) / 128, 256, 0, stream>>>(H0, W2T, support1, N_NODES);
    spmm2_softmax_kernel<<<N_NODES / 4, 256, 0, stream>>>(support1, row_ptr, pk, b2, out);
}

// Round 14
// 546.637 us; speedup vs baseline: 1.2502x; 1.0782x over previous
//
#include <hip/hip_runtime.h>
#include <hip/hip_bf16.h>

// ---------------- problem constants (match reference) ----------------
static constexpr int N_NODES = 100000;
static constexpr int N_EDGES = 3200000;
static constexpr int NFEAT   = 512;
static constexpr int NHID    = 256;
static constexpr int NCLASS  = 64;

static constexpr int SCAN_CHUNK = 2048;                       // 256 thr * 8 items
static constexpr int NB = (N_NODES + SCAN_CHUNK - 1) / SCAN_CHUNK; // 49

static constexpr int PARTS = 8;
static constexpr int NODES_PER_PART = N_NODES / PARTS;         // 12500
static constexpr int EDGES_PER_BLOCK = 1024;                   // 256 thr * 4
static constexpr int NCHUNK = N_EDGES / EDGES_PER_BLOCK;       // 3125

using short8 = __attribute__((ext_vector_type(8))) short;
using f32x4  = __attribute__((ext_vector_type(4))) float;
using fv4    = __attribute__((ext_vector_type(4))) float;
using fv2    = __attribute__((ext_vector_type(2))) float;
using iv4    = __attribute__((ext_vector_type(4))) int;
using fvec4  = __attribute__((ext_vector_type(4))) float;

__device__ __forceinline__ short f2bf_bits(float f) {
    __hip_bfloat16 h = __float2bfloat16(f);
    return *reinterpret_cast<short*>(&h);
}

// fp8 (OCP e4m3) helpers — gfx950 v_cvt_pk_* instructions
__device__ __forceinline__ unsigned char f2fp8(float v) {
    int p = __builtin_amdgcn_cvt_pk_fp8_f32(v, v, 0, false);
    return (unsigned char)(p & 0xff);
}

// acc2[0..3] += w * fp8[0..7] (packed fv2 -> v_pk_fma_f32)
__device__ __forceinline__ void fp8x8_acc_pk(int vx, int vy, float w, fv2* acc2) {
    fv2 w2; w2[0] = w; w2[1] = w;
    acc2[0] += w2 * __builtin_amdgcn_cvt_pk_f32_fp8(vx, false);
    acc2[1] += w2 * __builtin_amdgcn_cvt_pk_f32_fp8(vx, true);
    acc2[2] += w2 * __builtin_amdgcn_cvt_pk_f32_fp8(vy, false);
    acc2[3] += w2 * __builtin_amdgcn_cvt_pk_f32_fp8(vy, true);
}

// acc2[0..7] += w * fp8[0..15] (16 cols from one 16B gather)
__device__ __forceinline__ void fp8x16_acc_pk(iv4 v, float w, fv2* acc2) {
    fp8x8_acc_pk(v.x, v.y, w, acc2);
    fp8x8_acc_pk(v.z, v.w, w, acc2 + 4);
}

#define GLOBAL_TO_LDS(gsrc, ldst)                                                        \
    __builtin_amdgcn_global_load_lds((const __attribute__((address_space(1))) void*)(gsrc), \
                                     (__attribute__((address_space(3))) void*)(ldst), 16, 0, 0)

// ---------------- CSR build ----------------
__global__ __launch_bounds__(256) void hist_kernel(const int* __restrict__ edst,
                                                   int* __restrict__ counts) {
    int e0 = blockIdx.x * EDGES_PER_BLOCK + threadIdx.x * 4;
    iv4 d4 = __builtin_nontemporal_load((const iv4*)(edst + e0));
    atomicAdd(&counts[d4.x], 1);
    atomicAdd(&counts[d4.y], 1);
    atomicAdd(&counts[d4.z], 1);
    atomicAdd(&counts[d4.w], 1);
}

__global__ __launch_bounds__(256) void scan_part_kernel(const int* __restrict__ counts,
                                                        int* __restrict__ partials) {
    int b = blockIdx.x, t = threadIdx.x;
    int base = b * SCAN_CHUNK + t * 8;
    int s = 0;
#pragma unroll
    for (int j = 0; j < 8; ++j) {
        int i = base + j;
        if (i < N_NODES) s += counts[i];
    }
    __shared__ int sd[256];
    sd[t] = s;
    __syncthreads();
    for (int off = 128; off > 0; off >>= 1) {
        if (t < off) sd[t] += sd[t + off];
        __syncthreads();
    }
    if (t == 0) partials[b] = sd[0];
}

__global__ void scan_mid_kernel(int* __restrict__ partials) {
    if (threadIdx.x == 0) {
        int run = 0;
        for (int i = 0; i < NB; ++i) {
            int v = partials[i];
            partials[i] = run;
            run += v;
        }
    }
}

__global__ __launch_bounds__(256) void scan_final_kernel(int* __restrict__ counts_cursor,
                                                         int* __restrict__ row_ptr,
                                                         const int* __restrict__ partials) {
    int b = blockIdx.x, t = threadIdx.x;
    int base = b * SCAN_CHUNK + t * 8;
    int v[8];
    int tsum = 0;
#pragma unroll
    for (int j = 0; j < 8; ++j) {
        int i = base + j;
        v[j] = (i < N_NODES) ? counts_cursor[i] : 0;
        tsum += v[j];
    }
    __shared__ int sd[256];
    sd[t] = tsum;
    __syncthreads();
    for (int off = 1; off < 256; off <<= 1) {
        int x = (t >= off) ? sd[t - off] : 0;
        __syncthreads();
        sd[t] += x;
        __syncthreads();
    }
    int run = sd[t] - tsum + partials[b];
#pragma unroll
    for (int j = 0; j < 8; ++j) {
        int i = base + j;
        if (i < N_NODES) {
            row_ptr[i] = run;
            counts_cursor[i] = run;
        }
        run += v[j];
    }
    if (b == 0 && t == 0) row_ptr[N_NODES] = N_EDGES;
}

// Single-pass partitioned scatter, PLAIN stores (r11 config, known 146us).
// r13 post-mortem: nt stores REGRESSED (WRITE 165->220 MB) — gfx950 nt forces
// write-through/no-merge. 3.2M temporally-scattered 8B stores have a ~205 MB
// line-RMW floor; this kernel is at it. Scatter is closed.
__global__ __launch_bounds__(256) void scatter_part_kernel(const int* __restrict__ esrc,
                                                           const int* __restrict__ edst,
                                                           const float* __restrict__ ew,
                                                           int* __restrict__ cursor,
                                                           int2* __restrict__ pk) {
    int p = blockIdx.x & (PARTS - 1);
    int chunk = blockIdx.x >> 3;
    int e0 = chunk * EDGES_PER_BLOCK + threadIdx.x * 4;
    int lo = p * NODES_PER_PART, hi = lo + NODES_PER_PART;
    iv4   d4 = __builtin_nontemporal_load((const iv4*)(edst + e0));
    iv4   s4 = __builtin_nontemporal_load((const iv4*)(esrc + e0));
    fvec4 w4 = __builtin_nontemporal_load((const fvec4*)(ew + e0));
    int   dd[4] = {d4.x, d4.y, d4.z, d4.w};
    int   ss[4] = {s4.x, s4.y, s4.z, s4.w};
    float ww[4] = {w4.x, w4.y, w4.z, w4.w};
#pragma unroll
    for (int k = 0; k < 4; ++k) {
        if (dd[k] >= lo && dd[k] < hi) {
            int pos = atomicAdd(&cursor[dd[k]], 1);
            pk[pos] = make_int2(ss[k], __float_as_int(ww[k]));
        }
    }
}

// ---------------- small transpose+cast: W[K][N] f32 -> WT[N][K] bf16 ----------------
__global__ __launch_bounds__(256) void transpose_w_kernel(const float* __restrict__ W,
                                                          __hip_bfloat16* __restrict__ WT,
                                                          int K, int N) {
    int idx = blockIdx.x * 256 + threadIdx.x;
    if (idx < K * N) {
        int k = idx / N, n = idx % N;
        WT[(size_t)n * K + k] = __float2bfloat16(W[idx]);
    }
}

// ---------------- GEMM1: support0[M,256](fp8) = A[M,512](f32) @ W1T[256,512]^T -------
// r14: 8 waves (512 thr), BM=128 x BN=256 in ONE block -> A read exactly once
// (205 MB logical vs 410 with grid.y=2), per-wave 64x64 (acc=64 VGPR, no r6 cliff).
// LDS 64 KB (2x16 A + 2x16 B) -> 2 blocks/CU = 16 waves/CU. Double-buffered
// global_load_lds staging, same swizzles as r8 (remapped for 512 threads).
__global__ __launch_bounds__(512) void gemm1_mfma(const float* __restrict__ A,
                                                  const __hip_bfloat16* __restrict__ BT,
                                                  unsigned char* __restrict__ C8,
                                                  int M) {
    constexpr int K = NFEAT;   // 512
    constexpr int N = NHID;    // 256
    constexpr int BM = 128, BN = 256, BK = 32;
    constexpr int NSTEP = K / BK;  // 16
    __shared__ __align__(16) float          As[2][BM * BK];  // 2 x 16 KB
    __shared__ __align__(16) __hip_bfloat16 Bs[2][BN * BK];  // 2 x 16 KB
    const int tid = threadIdx.x;
    const int lane = tid & 63, wave = tid >> 6;   // 8 waves
    const int wr = wave >> 2, wc = wave & 3;      // 2 x 4 wave grid
    const int laneRow = lane & 15, laneK = lane >> 4;
    const int row0 = blockIdx.x * BM;

    f32x4 acc[4][4] = {};

    auto STAGE = [&](int step) {
        {
            float* dst = As[step & 1];
#pragma unroll
            for (int it = 0; it < 2; ++it) {
                int q = wave * 2 + it;            // 16 chunks of 1KB
                int r = q * 8 + (lane >> 3);
                int c16 = lane & 7;
                int src_c = (c16 ^ ((r & 3) << 1)) * 4;  // floats
                int rg = row0 + r; rg = (rg < M) ? rg : (M - 1);
                const float* src = A + (size_t)rg * K + step * BK + src_c;
                GLOBAL_TO_LDS(src, dst + q * 256 + lane * 4);
            }
        }
        {
            __hip_bfloat16* dst = Bs[step & 1];
#pragma unroll
            for (int it = 0; it < 2; ++it) {
                int idx = tid + it * 512;         // 1024 granules of 16B
                int n = idx >> 2;
                int gk = (idx & 3) ^ ((n >> 1) & 3);
                const __hip_bfloat16* src = BT + (size_t)n * K + step * BK + gk * 8;
                GLOBAL_TO_LDS(src, dst + (size_t)idx * 8);
            }
        }
    };

    STAGE(0);

#pragma unroll
    for (int t = 0; t < NSTEP; ++t) {
        __syncthreads();                  // drains vmcnt: As/Bs[t&1] ready; prev readers done
        if (t + 1 < NSTEP) STAGE(t + 1);  // async prefetch; drained at next barrier
        short8 af[4];
#pragma unroll
        for (int i = 0; i < 4; ++i) {
            int rr = wr * 64 + i * 16 + laneRow;
            int ck = laneK ^ (rr & 3);
            const float* ap = As[t & 1] + rr * BK + ck * 8;
            fv4 a0 = *(const fv4*)ap;
            fv4 a1 = *(const fv4*)(ap + 4);
            short8 v;
#pragma unroll
            for (int j = 0; j < 4; ++j) v[j] = f2bf_bits(a0[j]);
#pragma unroll
            for (int j = 0; j < 4; ++j) v[4 + j] = f2bf_bits(a1[j]);
            af[i] = v;
        }
        short8 bfr[4];
#pragma unroll
        for (int j = 0; j < 4; ++j) {
            int n = wc * 64 + j * 16 + laneRow;
            int pg = laneK ^ ((n >> 1) & 3);
            bfr[j] = *(const short8*)(Bs[t & 1] + n * BK + pg * 8);
        }
#pragma unroll
        for (int i = 0; i < 4; ++i)
#pragma unroll
            for (int j = 0; j < 4; ++j)
                acc[i][j] = __builtin_amdgcn_mfma_f32_16x16x32_bf16(af[i], bfr[j], acc[i][j], 0, 0, 0);
    }
    // epilogue: C/D layout col=lane&15, row=(lane>>4)*4+q
#pragma unroll
    for (int i = 0; i < 4; ++i) {
        int rbase = row0 + wr * 64 + i * 16 + laneK * 4;
#pragma unroll
        for (int j = 0; j < 4; ++j) {
            int col = wc * 64 + j * 16 + laneRow;
#pragma unroll
            for (int q = 0; q < 4; ++q) {
                int row = rbase + q;
                if (row < M) C8[(size_t)row * N + col] = f2fp8(acc[i][j][q]);
            }
        }
    }
}

// ---------------- GEMM2: support1[M,64](fp8) = H0[M,256](bf16) @ W2T[64,256]^T ------
__global__ __launch_bounds__(256) void gemm2_mfma(const __hip_bfloat16* __restrict__ A,
                                                  const __hip_bfloat16* __restrict__ BT,
                                                  unsigned char* __restrict__ C8,
                                                  int M) {
    constexpr int K = NHID;    // 256
    constexpr int N = NCLASS;  // 64
    constexpr int BM = 128;
    __shared__ __align__(16) __hip_bfloat16 Bs[N * K];  // 32 KB
    const int tid = threadIdx.x;
    const int lane = tid & 63, wave = tid >> 6;
    const int wr = wave >> 1, wc = wave & 1;
    const int laneRow = lane & 15, laneK = lane >> 4;
    const int row0 = blockIdx.x * BM;

#pragma unroll
    for (int it = 0; it < 8; ++it) {
        int idx = tid + it * 256;
        int n = idx >> 5;
        int kk = (idx & 31) ^ (n & 7);
        const __hip_bfloat16* src = BT + (size_t)n * K + kk * 8;
        GLOBAL_TO_LDS(src, Bs + (size_t)idx * 8);
    }

    int arow[4];
#pragma unroll
    for (int i = 0; i < 4; ++i) {
        int r = row0 + wr * 64 + i * 16 + laneRow;
        arow[i] = (r < M) ? r : (M - 1);
    }

    f32x4 acc[4][2] = {};
    __syncthreads();

#pragma unroll
    for (int k0 = 0; k0 < K; k0 += 32) {
        short8 af[4];
#pragma unroll
        for (int i = 0; i < 4; ++i)
            af[i] = *(const short8*)(A + (size_t)arow[i] * K + k0 + laneK * 8);
        short8 bfr[2];
#pragma unroll
        for (int j = 0; j < 2; ++j) {
            int n = wc * 32 + j * 16 + laneRow;
            int kkw = (k0 >> 3) + laneK;
            int pkk = kkw ^ (n & 7);
            bfr[j] = *(const short8*)(Bs + (size_t)n * 32 * 8 + pkk * 8);
        }
#pragma unroll
        for (int i = 0; i < 4; ++i)
#pragma unroll
            for (int j = 0; j < 2; ++j)
                acc[i][j] = __builtin_amdgcn_mfma_f32_16x16x32_bf16(af[i], bfr[j], acc[i][j], 0, 0, 0);
    }

#pragma unroll
    for (int i = 0; i < 4; ++i) {
        int rbase = row0 + wr * 64 + i * 16 + laneK * 4;
#pragma unroll
        for (int j = 0; j < 2; ++j) {
            int col = wc * 32 + j * 16 + laneRow;
#pragma unroll
            for (int q = 0; q < 4; ++q) {
                int row = rbase + q;
                if (row < M) C8[(size_t)row * N + col] = f2fp8(acc[i][j][q]);
            }
        }
    }
}

// ---------------- SPMM layer1: one wave = one node = FULL 256-col row.
// Lanes = 4 edge slots (lane>>4) x 16 chunks of 16 cols (16B gather per lane).
// x2 unroll -> 8 edges in flight per wave; packed fv2 accumulate (v_pk_fma_f32).
__global__ __launch_bounds__(256) void spmm1_kernel(const unsigned char* __restrict__ s0_8,
                                                    const int* __restrict__ row_ptr,
                                                    const int2* __restrict__ pk,
                                                    const float* __restrict__ b1,
                                                    __hip_bfloat16* __restrict__ H0) {
    int node = blockIdx.x * 4 + (threadIdx.x >> 6);
    int lane = threadIdx.x & 63;
    int j = lane >> 4;                 // edge slot 0..3
    int c = lane & 15;                 // column chunk (16 cols each) -> 256 cols
    int coff = c * 16;
    int beg = row_ptr[node], end = row_ptr[node + 1];
    fv2 acc2[8] = {};
    for (int base = beg; base + j < end; base += 8) {
        int2 pe0 = pk[base + j];
        int i1 = base + 4 + j;
        int2 pe1 = (i1 < end) ? pk[i1] : make_int2(0, 0);
        float w0 = __int_as_float(pe0.y);
        float w1 = __int_as_float(pe1.y);
        iv4 v0 = *(const iv4*)(s0_8 + (size_t)pe0.x * NHID + coff);
        iv4 v1 = *(const iv4*)(s0_8 + (size_t)pe1.x * NHID + coff);
        fp8x16_acc_pk(v0, w0, acc2);
        fp8x16_acc_pk(v1, w1, acc2);
    }
    float accf[16];
#pragma unroll
    for (int k = 0; k < 8; ++k) { accf[2 * k] = acc2[k][0]; accf[2 * k + 1] = acc2[k][1]; }
#pragma unroll
    for (int m = 16; m < 64; m <<= 1)
#pragma unroll
        for (int k = 0; k < 16; ++k) accf[k] += __shfl_xor(accf[k], m);
    if (lane < 16) {
        short8 o0, o1;
#pragma unroll
        for (int k = 0; k < 8; ++k)  o0[k] = f2bf_bits(fmaxf(accf[k] + b1[coff + k], 0.f));
#pragma unroll
        for (int k = 0; k < 8; ++k)  o1[k] = f2bf_bits(fmaxf(accf[8 + k] + b1[coff + 8 + k], 0.f));
        __hip_bfloat16* dst = H0 + (size_t)node * NHID + coff;
        *(short8*)dst = o0;
        *(short8*)(dst + 8) = o1;
    }
}

// ---------------- SPMM layer2 + bias + log_softmax (fp8 gather, 8x8, x2 unroll,
// packed fv2 accumulate) ---------------------------------------------------------------
__global__ __launch_bounds__(256) void spmm2_softmax_kernel(const unsigned char* __restrict__ s1_8,
                                                            const int* __restrict__ row_ptr,
                                                            const int2* __restrict__ pk,
                                                            const float* __restrict__ b2,
                                                            float* __restrict__ out) {
    int node = blockIdx.x * 4 + (threadIdx.x >> 6);
    int lane = threadIdx.x & 63;
    int j = lane >> 3;   // edge slot 0..7
    int c = lane & 7;    // class chunk (8 classes each)
    int beg = row_ptr[node], end = row_ptr[node + 1];
    fv2 acc2[4] = {};
    for (int base = beg; base + j < end; base += 16) {
        int2 pe0 = pk[base + j];
        int i1 = base + 8 + j;
        int2 pe1 = (i1 < end) ? pk[i1] : make_int2(0, 0);
        float w0 = __int_as_float(pe0.y);
        float w1 = __int_as_float(pe1.y);
        int2 v0 = *(const int2*)(s1_8 + (size_t)pe0.x * NCLASS + c * 8);
        int2 v1 = *(const int2*)(s1_8 + (size_t)pe1.x * NCLASS + c * 8);
        fp8x8_acc_pk(v0.x, v0.y, w0, acc2);
        fp8x8_acc_pk(v1.x, v1.y, w1, acc2);
    }
    float acc[8];
#pragma unroll
    for (int k = 0; k < 4; ++k) { acc[2 * k] = acc2[k][0]; acc[2 * k + 1] = acc2[k][1]; }
#pragma unroll
    for (int m = 8; m < 64; m <<= 1)
#pragma unroll
        for (int k = 0; k < 8; ++k) acc[k] += __shfl_xor(acc[k], m);

    fv4 blo = *(const fv4*)(b2 + c * 8);
    fv4 bhi = *(const fv4*)(b2 + c * 8 + 4);
    float z[8];
#pragma unroll
    for (int k = 0; k < 4; ++k) z[k] = acc[k] + blo[k];
#pragma unroll
    for (int k = 0; k < 4; ++k) z[4 + k] = acc[4 + k] + bhi[k];

    float mx = z[0];
#pragma unroll
    for (int k = 1; k < 8; ++k) mx = fmaxf(mx, z[k]);
#pragma unroll
    for (int m = 1; m < 8; m <<= 1) mx = fmaxf(mx, __shfl_xor(mx, m));
    float s = 0.f;
#pragma unroll
    for (int k = 0; k < 8; ++k) s += __expf(z[k] - mx);
#pragma unroll
    for (int m = 1; m < 8; m <<= 1) s += __shfl_xor(s, m);
    float lg = __logf(s);
    if (lane < 8) {
        f32x4 o0, o1;
#pragma unroll
        for (int k = 0; k < 4; ++k) o0[k] = z[k] - mx - lg;
#pragma unroll
        for (int k = 0; k < 4; ++k) o1[k] = z[4 + k] - mx - lg;
        float* dst = out + (size_t)node * NCLASS + c * 8;
        *(f32x4*)dst = o0;
        *(f32x4*)(dst + 4) = o1;
    }
}

// ---------------- host launch ----------------
extern "C" void kernel_launch(void* const* d_in, const int* in_sizes, int n_in,
                              void* d_out, int out_size, void* d_ws, size_t ws_size,
                              hipStream_t stream) {
    const float* x    = (const float*)d_in[0];
    const int*   esrc = (const int*)d_in[1];
    const int*   edst = (const int*)d_in[2];
    const float* ew   = (const float*)d_in[3];
    const float* W1   = (const float*)d_in[4];
    const float* b1   = (const float*)d_in[5];
    const float* W2   = (const float*)d_in[6];
    const float* b2   = (const float*)d_in[7];
    float* out = (float*)d_out;

    char* ws = (char*)d_ws;
    size_t off = 0;
    auto alloc = [&](size_t bytes) {
        size_t o = off;
        off = (off + bytes + 255) & ~(size_t)255;
        return o;
    };
    unsigned char* support0 = (unsigned char*)(ws + alloc((size_t)N_NODES * NHID));
    __hip_bfloat16* H0      = (__hip_bfloat16*)(ws + alloc((size_t)N_NODES * NHID * 2));
    unsigned char* support1 = (unsigned char*)(ws + alloc((size_t)N_NODES * NCLASS));
    int2*  pk         = (int2*)(ws + alloc((size_t)N_EDGES * 8));
    int*   row_ptr    = (int*)(ws + alloc((size_t)(N_NODES + 1) * 4));
    int*   cursor     = (int*)(ws + alloc((size_t)N_NODES * 4));
    int*   partials   = (int*)(ws + alloc(256 * 4));
    __hip_bfloat16* W1T = (__hip_bfloat16*)(ws + alloc((size_t)NHID * NFEAT * 2));
    __hip_bfloat16* W2T = (__hip_bfloat16*)(ws + alloc((size_t)NCLASS * NHID * 2));

    // --- weight transposes (bf16) ---
    transpose_w_kernel<<<(NFEAT * NHID + 255) / 256, 256, 0, stream>>>(W1, W1T, NFEAT, NHID);
    transpose_w_kernel<<<(NHID * NCLASS + 255) / 256, 256, 0, stream>>>(W2, W2T, NHID, NCLASS);

    // --- CSR build: single-pass hist -> scan -> single-pass scatter (plain stores) ---
    hipMemsetAsync(cursor, 0, (size_t)N_NODES * 4, stream);
    hist_kernel<<<NCHUNK, 256, 0, stream>>>(edst, cursor);
    scan_part_kernel<<<NB, 256, 0, stream>>>(cursor, partials);
    scan_mid_kernel<<<1, 64, 0, stream>>>(partials);
    scan_final_kernel<<<NB, 256, 0, stream>>>(cursor, row_ptr, partials);
    scatter_part_kernel<<<NCHUNK * PARTS, 256, 0, stream>>>(esrc, edst, ew, cursor, pk);

    // --- Layer 1 ---
    gemm1_mfma<<<(N_NODES + 127) / 128, 512, 0, stream>>>(x, W1T, support0, N_NODES);
    spmm1_kernel<<<N_NODES / 4, 256, 0, stream>>>(support0, row_ptr, pk, b1, H0);

    // --- Layer 2 ---
    gemm2_mfma<<<(N_NODES + 127) / 128, 256, 0, stream>>>(H0, W2T, support1, N_NODES);
    spmm2_softmax_kernel<<<N_NODES / 4, 256, 0, stream>>>(support1, row_ptr, pk, b2, out);
}